// Round 1
// baseline (44.219 us; speedup 1.0000x reference)
//
#include <hip/hip_runtime.h>
#include <math.h>

#define BB 2
#define NN 512
#define DD 128
#define ROWS (BB*NN)   // 1024
#define NR 4           // rows per block

__device__ __forceinline__ float sigmoidf(float z){ return 1.0f/(1.0f + __expf(-z)); }

// ---------------------------------------------------------------------------
// Kernel 1: per-row transforms.
//   h    = x @ W_lin^T + b_lin
//   hm1  = h @ W_m1[:, :128]^T + b_m1
//   dotL = h . W_att[0:128], dotR = h . W_att[128:256]
// grid 256 blocks x 128 threads; each block owns NR=4 rows; thread = output o.
// ---------------------------------------------------------------------------
__global__ __launch_bounds__(128) void k_rows(
    const float* __restrict__ x, const float* __restrict__ W_lin, const float* __restrict__ b_lin,
    const float* __restrict__ W_m1, const float* __restrict__ b_m1,
    const float* __restrict__ W_att,
    float* __restrict__ h, float* __restrict__ hm1,
    float* __restrict__ dotL, float* __restrict__ dotR)
{
    const int r0 = blockIdx.x * NR;
    const int t  = threadIdx.x;          // output index o
    __shared__ float xs[NR][DD];
    __shared__ float hs[NR][DD];
    __shared__ float red[2][2][NR];      // [wave][L/R][row]

    #pragma unroll
    for (int r = 0; r < NR; r++) xs[r][t] = x[(r0 + r) * DD + t];
    __syncthreads();

    float acc[NR];
    {
        float bl = b_lin[t];
        #pragma unroll
        for (int r = 0; r < NR; r++) acc[r] = bl;
        const float* wrow = W_lin + t * DD;
        for (int d = 0; d < DD; d += 4) {
            float4 w4 = *(const float4*)(wrow + d);
            #pragma unroll
            for (int r = 0; r < NR; r++) {
                float4 a4 = *(const float4*)(&xs[r][d]);
                acc[r] = fmaf(a4.x, w4.x, acc[r]);
                acc[r] = fmaf(a4.y, w4.y, acc[r]);
                acc[r] = fmaf(a4.z, w4.z, acc[r]);
                acc[r] = fmaf(a4.w, w4.w, acc[r]);
            }
        }
    }
    #pragma unroll
    for (int r = 0; r < NR; r++) { h[(r0 + r) * DD + t] = acc[r]; hs[r][t] = acc[r]; }

    // attention dot products (reduce over o = threads)
    {
        float wl = W_att[t], wr = W_att[DD + t];
        float pl[NR], pr[NR];
        #pragma unroll
        for (int r = 0; r < NR; r++) { pl[r] = acc[r] * wl; pr[r] = acc[r] * wr; }
        #pragma unroll
        for (int off = 32; off >= 1; off >>= 1) {
            #pragma unroll
            for (int r = 0; r < NR; r++) {
                pl[r] += __shfl_down(pl[r], off, 64);
                pr[r] += __shfl_down(pr[r], off, 64);
            }
        }
        int wid = t >> 6, lane = t & 63;
        if (lane == 0) {
            #pragma unroll
            for (int r = 0; r < NR; r++) { red[wid][0][r] = pl[r]; red[wid][1][r] = pr[r]; }
        }
    }
    __syncthreads();
    if (t < NR) {
        dotL[r0 + t] = red[0][0][t] + red[1][0][t];
        dotR[r0 + t] = red[0][1][t] + red[1][1][t];
    }

    // hm1 = h @ W_m1[:, :128]^T + b_m1   (W_m1 rows have stride 129)
    {
        float acc2[NR];
        float bm = b_m1[t];
        #pragma unroll
        for (int r = 0; r < NR; r++) acc2[r] = bm;
        const float* wrow = W_m1 + t * (DD + 1);
        for (int d = 0; d < DD; d += 4) {
            float w0 = wrow[d], w1 = wrow[d+1], w2 = wrow[d+2], w3 = wrow[d+3];
            #pragma unroll
            for (int r = 0; r < NR; r++) {
                float4 a4 = *(const float4*)(&hs[r][d]);
                acc2[r] = fmaf(a4.x, w0, acc2[r]);
                acc2[r] = fmaf(a4.y, w1, acc2[r]);
                acc2[r] = fmaf(a4.z, w2, acc2[r]);
                acc2[r] = fmaf(a4.w, w3, acc2[r]);
            }
        }
        #pragma unroll
        for (int r = 0; r < NR; r++) hm1[(r0 + r) * DD + t] = acc2[r];
    }
}

// ---------------------------------------------------------------------------
// Kernel 2: fused attention + message aggregation (the O(B*N^2*D) sweep).
//   att[n,m]  = sigmoid(dotL[n] + dotR[m] + adj*wAdj + bA)
//   aggm[n,d] = sum_m att * relu(hm1[m,d] + adj*wa1[d])
//   s_att[n]  = sum_m att
// Also copies adj to the second output. grid 256 x 512 threads.
// 8 wave-groups split the m-range; thread owns a d-pair (float2).
// ---------------------------------------------------------------------------
__global__ __launch_bounds__(512) void k_msg(
    const float* __restrict__ adj, const float* __restrict__ hm1,
    const float* __restrict__ dotL, const float* __restrict__ dotR,
    const float* __restrict__ W_m1, const float* __restrict__ W_att, const float* __restrict__ b_att,
    float* __restrict__ aggm, float* __restrict__ s_att, float* __restrict__ out_adj)
{
    const int r0   = blockIdx.x * NR;    // global row base (b*512 + n0)
    const int b    = r0 >> 9;            // batch
    const int t    = threadIdx.x;        // 0..511
    const int g    = t >> 6;             // wave group 0..7
    const int lane = t & 63;

    __shared__ float2 aa[NR][NN];        // (adj, att) per row, 16KB
    __shared__ float2 wa1s[64];          // W_m1[:,128] as d-pairs
    __shared__ float2 red[8][NR][64];    // partial aggm, 16KB

    if (t < 64)
        wa1s[t] = make_float2(W_m1[(2*t) * (DD+1) + DD], W_m1[(2*t+1) * (DD+1) + DD]);

    const float wAdj = W_att[2 * DD];
    const float bA   = b_att[0];

    // stage adj rows, copy to output, compute att
    #pragma unroll
    for (int i = 0; i < NR; i++) {
        float a = adj[(r0 + i) * NN + t];
        out_adj[(r0 + i) * NN + t] = a;
        float z = dotL[r0 + i] + dotR[b * NN + t] + a * wAdj + bA;
        aa[i][t] = make_float2(a, sigmoidf(z));
    }
    __syncthreads();

    // s_att: wave g < NR reduces row g
    if (g < NR) {
        float s = 0.f;
        #pragma unroll
        for (int k = 0; k < 8; k++) s += aa[g][lane + 64 * k].y;
        #pragma unroll
        for (int off = 32; off >= 1; off >>= 1) s += __shfl_down(s, off, 64);
        if (lane == 0) s_att[r0 + g] = s;
    }

    // main sweep over neighbors m
    float2 ag[NR];
    #pragma unroll
    for (int r = 0; r < NR; r++) ag[r] = make_float2(0.f, 0.f);
    float2 wa = wa1s[lane];
    const float* hbase = hm1 + (size_t)b * NN * DD + 2 * lane;
    for (int m = g; m < NN; m += 8) {
        float2 hv = *(const float2*)(hbase + m * DD);
        #pragma unroll
        for (int r = 0; r < NR; r++) {
            float2 at = aa[r][m];                       // broadcast ds_read_b64
            float u0 = fmaxf(fmaf(at.x, wa.x, hv.x), 0.f);
            float u1 = fmaxf(fmaf(at.x, wa.y, hv.y), 0.f);
            ag[r].x = fmaf(at.y, u0, ag[r].x);
            ag[r].y = fmaf(at.y, u1, ag[r].y);
        }
    }
    #pragma unroll
    for (int r = 0; r < NR; r++) red[g][r][lane] = ag[r];
    __syncthreads();

    // combine 8 group partials; 512 threads -> one (r, o) each
    {
        int r = t >> 7, o = t & 127;
        float s = 0.f;
        #pragma unroll
        for (int gg = 0; gg < 8; gg++)
            s += ((const float*)&red[gg][r][0])[o];
        aggm[(r0 + r) * DD + o] = s;
    }
}

// ---------------------------------------------------------------------------
// Kernel 3: output network + residual + layernorm + relu.
//   v1 = aggm @ W_m2^T + b_m2 * s_att
//   v2 = relu(v1 @ W_o1^T + b_o1)
//   v3 = v2 @ W_o2^T + b_o2
//   out = relu(LN(h + v3) * g + b)
// ---------------------------------------------------------------------------
__global__ __launch_bounds__(128) void k_out(
    const float* __restrict__ h, const float* __restrict__ aggm, const float* __restrict__ s_att,
    const float* __restrict__ W_m2, const float* __restrict__ b_m2,
    const float* __restrict__ W_o1, const float* __restrict__ b_o1,
    const float* __restrict__ W_o2, const float* __restrict__ b_o2,
    const float* __restrict__ ln_g, const float* __restrict__ ln_b,
    float* __restrict__ out)
{
    const int r0 = blockIdx.x * NR;
    const int t  = threadIdx.x;
    __shared__ float s0[NR][DD];
    __shared__ float s1[NR][DD];
    __shared__ float redm[2][2][NR];

    #pragma unroll
    for (int r = 0; r < NR; r++) s0[r][t] = aggm[(r0 + r) * DD + t];
    __syncthreads();

    float v[NR];
    {   // v1 = aggm @ W_m2^T + b_m2 * s_att
        float bm = b_m2[t];
        #pragma unroll
        for (int r = 0; r < NR; r++) v[r] = bm * s_att[r0 + r];
        const float* wrow = W_m2 + t * DD;
        for (int d = 0; d < DD; d += 4) {
            float4 w4 = *(const float4*)(wrow + d);
            #pragma unroll
            for (int r = 0; r < NR; r++) {
                float4 a4 = *(const float4*)(&s0[r][d]);
                v[r] = fmaf(a4.x, w4.x, v[r]);
                v[r] = fmaf(a4.y, w4.y, v[r]);
                v[r] = fmaf(a4.z, w4.z, v[r]);
                v[r] = fmaf(a4.w, w4.w, v[r]);
            }
        }
    }
    #pragma unroll
    for (int r = 0; r < NR; r++) s1[r][t] = v[r];
    __syncthreads();

    {   // v2 = relu(v1 @ W_o1^T + b_o1)
        float bo = b_o1[t];
        #pragma unroll
        for (int r = 0; r < NR; r++) v[r] = bo;
        const float* wrow = W_o1 + t * DD;
        for (int d = 0; d < DD; d += 4) {
            float4 w4 = *(const float4*)(wrow + d);
            #pragma unroll
            for (int r = 0; r < NR; r++) {
                float4 a4 = *(const float4*)(&s1[r][d]);
                v[r] = fmaf(a4.x, w4.x, v[r]);
                v[r] = fmaf(a4.y, w4.y, v[r]);
                v[r] = fmaf(a4.z, w4.z, v[r]);
                v[r] = fmaf(a4.w, w4.w, v[r]);
            }
        }
        #pragma unroll
        for (int r = 0; r < NR; r++) v[r] = fmaxf(v[r], 0.f);
    }
    #pragma unroll
    for (int r = 0; r < NR; r++) s0[r][t] = v[r];   // safe: s0 last read before prev sync
    __syncthreads();

    {   // v3 = v2 @ W_o2^T + b_o2
        float bo = b_o2[t];
        #pragma unroll
        for (int r = 0; r < NR; r++) v[r] = bo;
        const float* wrow = W_o2 + t * DD;
        for (int d = 0; d < DD; d += 4) {
            float4 w4 = *(const float4*)(wrow + d);
            #pragma unroll
            for (int r = 0; r < NR; r++) {
                float4 a4 = *(const float4*)(&s0[r][d]);
                v[r] = fmaf(a4.x, w4.x, v[r]);
                v[r] = fmaf(a4.y, w4.y, v[r]);
                v[r] = fmaf(a4.z, w4.z, v[r]);
                v[r] = fmaf(a4.w, w4.w, v[r]);
            }
        }
    }
    // residual
    #pragma unroll
    for (int r = 0; r < NR; r++) v[r] += h[(r0 + r) * DD + t];

    // layernorm over d (threads) per row
    float p1[NR], p2[NR];
    #pragma unroll
    for (int r = 0; r < NR; r++) { p1[r] = v[r]; p2[r] = v[r] * v[r]; }
    #pragma unroll
    for (int off = 32; off >= 1; off >>= 1) {
        #pragma unroll
        for (int r = 0; r < NR; r++) {
            p1[r] += __shfl_xor(p1[r], off, 64);
            p2[r] += __shfl_xor(p2[r], off, 64);
        }
    }
    int wid = t >> 6;
    if ((t & 63) == 0) {
        #pragma unroll
        for (int r = 0; r < NR; r++) { redm[wid][0][r] = p1[r]; redm[wid][1][r] = p2[r]; }
    }
    __syncthreads();
    float gg = ln_g[t], bb = ln_b[t];
    #pragma unroll
    for (int r = 0; r < NR; r++) {
        float sum = redm[0][0][r] + redm[1][0][r];
        float sq  = redm[0][1][r] + redm[1][1][r];
        float mu  = sum * (1.0f / DD);
        float var = sq * (1.0f / DD) - mu * mu;
        float inv = rsqrtf(var + 1e-5f);
        out[(r0 + r) * DD + t] = fmaxf(fmaf((v[r] - mu) * inv, gg, bb), 0.f);
    }
}

extern "C" void kernel_launch(void* const* d_in, const int* in_sizes, int n_in,
                              void* d_out, int out_size, void* d_ws, size_t ws_size,
                              hipStream_t stream)
{
    (void)in_sizes; (void)n_in; (void)out_size; (void)ws_size;
    const float* x     = (const float*)d_in[0];
    const float* adj   = (const float*)d_in[1];
    const float* W_lin = (const float*)d_in[2];
    const float* b_lin = (const float*)d_in[3];
    const float* W_m1  = (const float*)d_in[4];
    const float* b_m1  = (const float*)d_in[5];
    const float* W_m2  = (const float*)d_in[6];
    const float* b_m2  = (const float*)d_in[7];
    const float* W_att = (const float*)d_in[8];
    const float* b_att = (const float*)d_in[9];
    const float* W_o1  = (const float*)d_in[10];
    const float* b_o1  = (const float*)d_in[11];
    const float* W_o2  = (const float*)d_in[12];
    const float* b_o2  = (const float*)d_in[13];
    const float* ln_g  = (const float*)d_in[14];
    const float* ln_b  = (const float*)d_in[15];

    float* out     = (float*)d_out;
    float* out_adj = out + ROWS * DD;         // second output: adj passthrough

    float* ws   = (float*)d_ws;
    float* h    = ws;                          // 131072
    float* hm1  = ws + 131072;                 // 131072
    float* dotL = ws + 262144;                 // 1024
    float* dotR = ws + 263168;                 // 1024
    float* aggm = ws + 264192;                 // 131072
    float* satt = ws + 395264;                 // 1024

    hipLaunchKernelGGL(k_rows, dim3(ROWS / NR), dim3(128), 0, stream,
                       x, W_lin, b_lin, W_m1, b_m1, W_att, h, hm1, dotL, dotR);
    hipLaunchKernelGGL(k_msg, dim3(ROWS / NR), dim3(512), 0, stream,
                       adj, hm1, dotL, dotR, W_m1, W_att, b_att, aggm, satt, out_adj);
    hipLaunchKernelGGL(k_out, dim3(ROWS / NR), dim3(128), 0, stream,
                       h, aggm, satt, W_m2, b_m2, W_o1, b_o1, W_o2, b_o2, ln_g, ln_b, out);
}